// Round 1
// baseline (466.206 us; speedup 1.0000x reference)
//
#include <hip/hip_runtime.h>
#include <hip/hip_bf16.h>

#define N_HIST 65536
#define CAP 2048

__device__ __forceinline__ unsigned flip_f32(float f) {
  unsigned u = __float_as_uint(f);
  return (u & 0x80000000u) ? ~u : (u | 0x80000000u);
}

// GEMV: 8 lanes per row, 4 float4 per lane (row = 128 floats).
// Wave of 64 handles 8 rows per iteration; loads are 128B-contiguous per
// (row, quarter) chunk -> fully coalesced.
__global__ __launch_bounds__(256) void gemv_hist_kernel(
    const float* __restrict__ item, const float* __restrict__ user,
    const int* __restrict__ uid, float* __restrict__ scores,
    unsigned* __restrict__ hist, int n_items) {
  const int lane = threadIdx.x & 63;
  const int sub  = lane & 7;    // position within row (float4 col = sub + 8j)
  const int rloc = lane >> 3;   // 0..7: which row of the wave's group
  const int wid  = blockIdx.x * (blockDim.x >> 6) + (threadIdx.x >> 6);
  const int nw   = gridDim.x * (blockDim.x >> 6);

  const float4* __restrict__ u4 = (const float4*)(user + (size_t)(*uid) * 128);
  const float4 ua = u4[sub];
  const float4 ub = u4[sub + 8];
  const float4 uc = u4[sub + 16];
  const float4 ud = u4[sub + 24];

  for (size_t base = (size_t)wid * 8; base < (size_t)n_items;
       base += (size_t)nw * 8) {
    const size_t r = base + rloc;   // n_items divisible by 8
    const float4* __restrict__ p = (const float4*)(item + r * 128);
    float4 a = p[sub];
    float4 b = p[sub + 8];
    float4 c = p[sub + 16];
    float4 d = p[sub + 24];
    float s = a.x * ua.x + a.y * ua.y + a.z * ua.z + a.w * ua.w;
    s += b.x * ub.x + b.y * ub.y + b.z * ub.z + b.w * ub.w;
    s += c.x * uc.x + c.y * uc.y + c.z * uc.z + c.w * uc.w;
    s += d.x * ud.x + d.y * ud.y + d.z * ud.z + d.w * ud.w;
    s += __shfl_xor(s, 1, 8);
    s += __shfl_xor(s, 2, 8);
    s += __shfl_xor(s, 4, 8);
    if (sub == 0) {
      scores[r] = s;
      atomicAdd(&hist[flip_f32(s) >> 16], 1u);
    }
  }
}

// Single block: find largest bin T with suffix_count(T) >= k.
__global__ __launch_bounds__(1024) void scan_hist_kernel(
    const unsigned* __restrict__ hist, const int* __restrict__ kptr,
    unsigned* __restrict__ meta) {
  __shared__ unsigned part[1024];
  __shared__ int pmax, tmax;
  const int t = threadIdx.x;
  const unsigned k = (unsigned)(*kptr);

  unsigned s = 0;
  const int b0 = t * 64;
  for (int j = 0; j < 64; ++j) s += hist[b0 + j];
  part[t] = s;
  if (t == 0) { pmax = -1; tmax = -1; }
  __syncthreads();

  // Hillis-Steele inclusive suffix sum over the 1024 chunk sums.
  for (int off = 1; off < 1024; off <<= 1) {
    unsigned v = (t + off < 1024) ? part[t + off] : 0u;
    __syncthreads();
    part[t] += v;
    __syncthreads();
  }

  if (part[t] >= k) atomicMax(&pmax, t);
  __syncthreads();
  const int p = pmax;                      // chunk containing threshold bin
  const unsigned nxt = (p < 1023) ? part[p + 1] : 0u;
  if (t < 64) {
    unsigned sv = nxt;
    for (int b = p * 64 + t; b < p * 64 + 64; ++b) sv += hist[b];
    if (sv >= k) atomicMax(&tmax, t);      // largest in-chunk bin meeting k
  }
  __syncthreads();
  if (t == 0) meta[1] = (unsigned)(p * 64 + tmax);
}

__global__ __launch_bounds__(256) void collect_kernel(
    const float* __restrict__ scores, unsigned* __restrict__ meta,
    unsigned long long* __restrict__ cand, int n_items) {
  const unsigned T = meta[1];
  for (int i = blockIdx.x * blockDim.x + threadIdx.x; i < n_items;
       i += gridDim.x * blockDim.x) {
    const unsigned u = flip_f32(scores[i]);
    if ((u >> 16) >= T) {
      const unsigned pos = atomicAdd(&meta[0], 1u);
      if (pos < CAP)
        cand[pos] = ((unsigned long long)u << 32) |
                    (unsigned long long)(0xFFFFFFFFu - (unsigned)i);
    }
  }
}

// Single block bitonic sort of up to CAP u64 keys, descending.
// key = (flipped_score << 32) | (0xFFFFFFFF - idx): descending key order ==
// descending score, ties broken by ascending index (matches jax top_k).
__global__ __launch_bounds__(1024) void topk_sort_kernel(
    const unsigned long long* __restrict__ cand,
    const unsigned* __restrict__ meta, const int* __restrict__ kptr,
    int* __restrict__ out) {
  __shared__ unsigned long long keys[CAP];
  const int t = threadIdx.x;
  unsigned m = meta[0];
  if (m > CAP) m = CAP;
  for (int i = t; i < CAP; i += 1024)
    keys[i] = (i < (int)m) ? cand[i] : 0ULL;
  __syncthreads();

  for (unsigned size = 2; size <= CAP; size <<= 1) {
    for (unsigned stride = size >> 1; stride >= 1; stride >>= 1) {
      const unsigned pos = 2 * t - (t & (stride - 1));
      const bool up = ((pos & size) == 0);
      const unsigned long long a = keys[pos];
      const unsigned long long b = keys[pos + stride];
      if ((a < b) == up) { keys[pos] = b; keys[pos + stride] = a; }
      __syncthreads();
    }
  }
  const int k = *kptr;
  if (t < k)
    out[t] = (int)(0xFFFFFFFFu - (unsigned)(keys[t] & 0xFFFFFFFFull));
}

extern "C" void kernel_launch(void* const* d_in, const int* in_sizes, int n_in,
                              void* d_out, int out_size, void* d_ws, size_t ws_size,
                              hipStream_t stream) {
  const int*   uid  = (const int*)d_in[0];
  const float* user = (const float*)d_in[1];
  const float* item = (const float*)d_in[2];
  const int*   kptr = (const int*)d_in[3];
  const int n_items = in_sizes[2] / 128;

  char* base = (char*)d_ws;
  const size_t score_bytes = ((size_t)n_items * 4 + 255) & ~(size_t)255;
  float*              scores = (float*)base;
  unsigned*           hist   = (unsigned*)(base + score_bytes);
  unsigned*           meta   = (unsigned*)(base + score_bytes + N_HIST * 4);
  unsigned long long* cand   =
      (unsigned long long*)(base + score_bytes + N_HIST * 4 + 256);

  // ws is poisoned once and never restored between replays: zero hist+meta.
  hipMemsetAsync(base + score_bytes, 0, N_HIST * 4 + 256, stream);

  gemv_hist_kernel<<<2048, 256, 0, stream>>>(item, user, uid, scores, hist,
                                             n_items);
  scan_hist_kernel<<<1, 1024, 0, stream>>>(hist, kptr, meta);
  collect_kernel<<<1024, 256, 0, stream>>>(scores, meta, cand, n_items);
  topk_sort_kernel<<<1, 1024, 0, stream>>>(cand, meta, kptr, (int*)d_out);
}

// Round 2
// 147.089 us; speedup vs baseline: 3.1695x; 3.1695x over previous
//
#include <hip/hip_runtime.h>
#include <hip/hip_bf16.h>

#define N_HIST 65536
#define CAP 2048

__device__ __forceinline__ unsigned flip_f32(float f) {
  unsigned u = __float_as_uint(f);
  return (u & 0x80000000u) ? ~u : (u | 0x80000000u);
}

// Pure GEMV: 8 lanes per row, 4 float4 per lane (row = 128 floats).
// No atomics in the streaming path (R0 lesson: fused hist atomics serialized
// the whole kernel via in-order vmcnt completion + same-line atomic chains).
__global__ __launch_bounds__(256) void gemv_kernel(
    const float* __restrict__ item, const float* __restrict__ user,
    const int* __restrict__ uid, float* __restrict__ scores, int n_items) {
  const int lane = threadIdx.x & 63;
  const int sub  = lane & 7;    // position within row (float4 col = sub + 8j)
  const int rloc = lane >> 3;   // 0..7: which row of the wave's group
  const int wid  = blockIdx.x * (blockDim.x >> 6) + (threadIdx.x >> 6);
  const int nw   = gridDim.x * (blockDim.x >> 6);

  const float4* __restrict__ u4 = (const float4*)(user + (size_t)(*uid) * 128);
  const float4 ua = u4[sub];
  const float4 ub = u4[sub + 8];
  const float4 uc = u4[sub + 16];
  const float4 ud = u4[sub + 24];

  for (size_t base = (size_t)wid * 8; base < (size_t)n_items;
       base += (size_t)nw * 8) {
    const size_t r = base + rloc;   // n_items divisible by 8
    const float4* __restrict__ p = (const float4*)(item + r * 128);
    float4 a = p[sub];
    float4 b = p[sub + 8];
    float4 c = p[sub + 16];
    float4 d = p[sub + 24];
    float s = a.x * ua.x + a.y * ua.y + a.z * ua.z + a.w * ua.w;
    s += b.x * ub.x + b.y * ub.y + b.z * ub.z + b.w * ub.w;
    s += c.x * uc.x + c.y * uc.y + c.z * uc.z + c.w * uc.w;
    s += d.x * ud.x + d.y * ud.y + d.z * ud.z + d.w * ud.w;
    s += __shfl_xor(s, 1, 8);
    s += __shfl_xor(s, 2, 8);
    s += __shfl_xor(s, 4, 8);
    if (sub == 0) scores[r] = s;   // 8 lanes -> one 32B contiguous segment
  }
}

// LDS-privatized histogram: 65536 u16 bins packed in 32768 u32 (128 KB LDS).
// 64 blocks -> <=16K items/block (u16 never overflows), and the global flush
// has at most 64 same-address atomics per bin instead of ~2000.
__global__ __launch_bounds__(1024) void hist_kernel(
    const float* __restrict__ scores, unsigned* __restrict__ hist, int n4) {
  __shared__ unsigned lh[N_HIST / 2];
  for (int i = threadIdx.x; i < N_HIST / 2; i += 1024) lh[i] = 0;
  __syncthreads();
  const float4* __restrict__ s4 = (const float4*)scores;
  for (int i = blockIdx.x * blockDim.x + threadIdx.x; i < n4;
       i += gridDim.x * blockDim.x) {
    float4 v = s4[i];
    unsigned b0 = flip_f32(v.x) >> 16, b1 = flip_f32(v.y) >> 16;
    unsigned b2 = flip_f32(v.z) >> 16, b3 = flip_f32(v.w) >> 16;
    atomicAdd(&lh[b0 >> 1], 1u << ((b0 & 1) * 16));
    atomicAdd(&lh[b1 >> 1], 1u << ((b1 & 1) * 16));
    atomicAdd(&lh[b2 >> 1], 1u << ((b2 & 1) * 16));
    atomicAdd(&lh[b3 >> 1], 1u << ((b3 & 1) * 16));
  }
  __syncthreads();
  for (int i = threadIdx.x; i < N_HIST / 2; i += 1024) {
    unsigned v = lh[i];
    if (v & 0xFFFFu) atomicAdd(&hist[2 * i], v & 0xFFFFu);
    if (v >> 16)     atomicAdd(&hist[2 * i + 1], v >> 16);
  }
}

// Single block: find largest bin T with suffix_count(T) >= k.
__global__ __launch_bounds__(1024) void scan_hist_kernel(
    const unsigned* __restrict__ hist, const int* __restrict__ kptr,
    unsigned* __restrict__ meta) {
  __shared__ unsigned part[1024];
  __shared__ int pmax, tmax;
  const int t = threadIdx.x;
  const unsigned k = (unsigned)(*kptr);

  unsigned s = 0;
  const int b0 = t * 64;
  for (int j = 0; j < 64; ++j) s += hist[b0 + j];
  part[t] = s;
  if (t == 0) { pmax = -1; tmax = -1; }
  __syncthreads();

  // Hillis-Steele inclusive suffix sum over the 1024 chunk sums.
  for (int off = 1; off < 1024; off <<= 1) {
    unsigned v = (t + off < 1024) ? part[t + off] : 0u;
    __syncthreads();
    part[t] += v;
    __syncthreads();
  }

  if (part[t] >= k) atomicMax(&pmax, t);
  __syncthreads();
  const int p = pmax;                      // chunk containing threshold bin
  const unsigned nxt = (p < 1023) ? part[p + 1] : 0u;
  if (t < 64) {
    unsigned sv = nxt;
    for (int b = p * 64 + t; b < p * 64 + 64; ++b) sv += hist[b];
    if (sv >= k) atomicMax(&tmax, t);      // largest in-chunk bin meeting k
  }
  __syncthreads();
  if (t == 0) meta[1] = (unsigned)(p * 64 + tmax);
}

__global__ __launch_bounds__(256) void collect_kernel(
    const float* __restrict__ scores, unsigned* __restrict__ meta,
    unsigned long long* __restrict__ cand, int n_items) {
  const unsigned T = meta[1];
  for (int i = blockIdx.x * blockDim.x + threadIdx.x; i < n_items;
       i += gridDim.x * blockDim.x) {
    const unsigned u = flip_f32(scores[i]);
    if ((u >> 16) >= T) {
      const unsigned pos = atomicAdd(&meta[0], 1u);
      if (pos < CAP)
        cand[pos] = ((unsigned long long)u << 32) |
                    (unsigned long long)(0xFFFFFFFFu - (unsigned)i);
    }
  }
}

// Single block bitonic sort of up to CAP u64 keys, descending.
// key = (flipped_score << 32) | (0xFFFFFFFF - idx): descending key order ==
// descending score, ties broken by ascending index (matches jax top_k).
__global__ __launch_bounds__(1024) void topk_sort_kernel(
    const unsigned long long* __restrict__ cand,
    const unsigned* __restrict__ meta, const int* __restrict__ kptr,
    int* __restrict__ out) {
  __shared__ unsigned long long keys[CAP];
  const int t = threadIdx.x;
  unsigned m = meta[0];
  if (m > CAP) m = CAP;
  for (int i = t; i < CAP; i += 1024)
    keys[i] = (i < (int)m) ? cand[i] : 0ULL;
  __syncthreads();

  for (unsigned size = 2; size <= CAP; size <<= 1) {
    for (unsigned stride = size >> 1; stride >= 1; stride >>= 1) {
      const unsigned pos = 2 * t - (t & (stride - 1));
      const bool up = ((pos & size) == 0);
      const unsigned long long a = keys[pos];
      const unsigned long long b = keys[pos + stride];
      if ((a < b) == up) { keys[pos] = b; keys[pos + stride] = a; }
      __syncthreads();
    }
  }
  const int k = *kptr;
  if (t < k)
    out[t] = (int)(0xFFFFFFFFu - (unsigned)(keys[t] & 0xFFFFFFFFull));
}

extern "C" void kernel_launch(void* const* d_in, const int* in_sizes, int n_in,
                              void* d_out, int out_size, void* d_ws, size_t ws_size,
                              hipStream_t stream) {
  const int*   uid  = (const int*)d_in[0];
  const float* user = (const float*)d_in[1];
  const float* item = (const float*)d_in[2];
  const int*   kptr = (const int*)d_in[3];
  const int n_items = in_sizes[2] / 128;

  char* base = (char*)d_ws;
  const size_t score_bytes = ((size_t)n_items * 4 + 255) & ~(size_t)255;
  float*              scores = (float*)base;
  unsigned*           hist   = (unsigned*)(base + score_bytes);
  unsigned*           meta   = (unsigned*)(base + score_bytes + N_HIST * 4);
  unsigned long long* cand   =
      (unsigned long long*)(base + score_bytes + N_HIST * 4 + 256);

  // ws is poisoned once and never restored between replays: zero hist+meta.
  hipMemsetAsync(base + score_bytes, 0, N_HIST * 4 + 256, stream);

  gemv_kernel<<<2048, 256, 0, stream>>>(item, user, uid, scores, n_items);
  hist_kernel<<<64, 1024, 0, stream>>>(scores, hist, n_items / 4);
  scan_hist_kernel<<<1, 1024, 0, stream>>>(hist, kptr, meta);
  collect_kernel<<<1024, 256, 0, stream>>>(scores, meta, cand, n_items);
  topk_sort_kernel<<<1, 1024, 0, stream>>>(cand, meta, kptr, (int*)d_out);
}